// Round 12
// baseline (386.245 us; speedup 1.0000x reference)
//
#include <hip/hip_runtime.h>

#define B_   2
#define S_   2048
#define H_   2560
#define NH_  8
#define NKV_ 4
#define D_   256
#define SW_  1024

// qkv row layout (fp16, stride 4096): [0,2048) Q heads, [2048,3072) K, [3072,4096) V
#define QKV_LD 4096

typedef __attribute__((ext_vector_type(8))) short    short8;
typedef __attribute__((ext_vector_type(8))) _Float16 half8;
typedef __attribute__((ext_vector_type(4))) _Float16 half4;
typedef __attribute__((ext_vector_type(4))) float    floatx4;
typedef __attribute__((ext_vector_type(2))) float    floatx2;

typedef unsigned int __attribute__((address_space(1))) as1_uint;
typedef unsigned int __attribute__((address_space(3))) as3_uint;

static __device__ __forceinline__ void async16(const void* g, void* l) {
    __builtin_amdgcn_global_load_lds((const as1_uint*)g, (as3_uint*)l, 16, 0, 0);
}

// 16-lane reductions via DPP row_ror (VALU-speed) instead of __shfl_xor
// (ds_bpermute). Commutative reduction: ror:{8,4,2,1} covers all 16 lanes.
static __device__ __forceinline__ float red16_max(float v) {
    int x;
    x = __builtin_amdgcn_update_dpp(0, __float_as_int(v), 0x128, 0xf, 0xf, true);
    v = fmaxf(v, __int_as_float(x));
    x = __builtin_amdgcn_update_dpp(0, __float_as_int(v), 0x124, 0xf, 0xf, true);
    v = fmaxf(v, __int_as_float(x));
    x = __builtin_amdgcn_update_dpp(0, __float_as_int(v), 0x122, 0xf, 0xf, true);
    v = fmaxf(v, __int_as_float(x));
    x = __builtin_amdgcn_update_dpp(0, __float_as_int(v), 0x121, 0xf, 0xf, true);
    v = fmaxf(v, __int_as_float(x));
    return v;
}
static __device__ __forceinline__ float red16_sum(float v) {
    int x;
    x = __builtin_amdgcn_update_dpp(0, __float_as_int(v), 0x128, 0xf, 0xf, true);
    v += __int_as_float(x);
    x = __builtin_amdgcn_update_dpp(0, __float_as_int(v), 0x124, 0xf, 0xf, true);
    v += __int_as_float(x);
    x = __builtin_amdgcn_update_dpp(0, __float_as_int(v), 0x122, 0xf, 0xf, true);
    v += __int_as_float(x);
    x = __builtin_amdgcn_update_dpp(0, __float_as_int(v), 0x121, 0xf, 0xf, true);
    v += __int_as_float(x);
    return v;
}

// ---------------------------------------------------------------------------
// Fused fp32 -> fp16 conversion for all 5 tensors (blockIdx.y selects tensor)
// ---------------------------------------------------------------------------
__global__ __launch_bounds__(256) void conv_all(
    const float* __restrict__ s0, const float* __restrict__ s1,
    const float* __restrict__ s2, const float* __restrict__ s3,
    const float* __restrict__ s4,
    _Float16* __restrict__ d0, _Float16* __restrict__ d1,
    _Float16* __restrict__ d2, _Float16* __restrict__ d3,
    _Float16* __restrict__ d4)
{
    const float* src; _Float16* dst; int n4;
    switch (blockIdx.y) {
        case 0:  src = s0; dst = d0; n4 = 4096 * 2560 / 4; break;   // hidden
        case 1:  src = s1; dst = d1; n4 = 2048 * 2560 / 4; break;   // Wq
        case 2:  src = s2; dst = d2; n4 = 1024 * 2560 / 4; break;   // Wk
        case 3:  src = s3; dst = d3; n4 = 1024 * 2560 / 4; break;   // Wv
        default: src = s4; dst = d4; n4 = 2560 * 2048 / 4; break;   // Wo
    }
    for (int i = blockIdx.x * 256 + threadIdx.x; i < n4; i += gridDim.x * 256) {
        floatx4 v = *(const floatx4*)(src + (size_t)i * 4);
        half4 h = { (_Float16)v.x, (_Float16)v.y, (_Float16)v.z, (_Float16)v.w };
        *(half4*)(dst + (size_t)i * 4) = h;
    }
}

// ---------------------------------------------------------------------------
// fp16 GEMM, 256x256 tile, BK=64, 8 waves (2Mx4N), 8-phase schedule.
// R12 change: LDS-STAGED COALESCED C-WRITE. The old epilogue issued 128
// scattered 2B (or 4B) stores per thread (wave = 4 rows x 32B fragments,
// ~25% segment efficiency) -- a multi-us serialized tail per block. Now:
// acc -> LDS (128 KB staging buffers are dead after the K-loop; 256x256
// fp16 fits exactly), barrier, then 16x half8 fully-coalesced stores per
// thread (1 KB/wave). fp32 path: two 128-row passes (256 KB doesn't fit).
// ---------------------------------------------------------------------------
template <int C_FP32>
__global__ __launch_bounds__(512, 2) void gemm256(
    const _Float16* __restrict__ A,    // [M][K]
    const _Float16* __restrict__ Bm,   // [N][K]
    void* __restrict__ Cv,             // [M][N]
    int M, int N, int K, int NBX)
{
    (void)M;
    __shared__ __align__(16) _Float16 SM[4][256 * 64];   // 4 x 32 KB (A0,A1,B0,B1 / C-stage)

    const int tid  = threadIdx.x;
    const int lane = tid & 63, w = tid >> 6;
    const int wr = w >> 2, wc = w & 3;                   // 2 x 4 wave grid
    const int quad = lane >> 4, l16 = lane & 15;

    const int nwg = gridDim.x, cpx = nwg >> 3;
    const int swz = (blockIdx.x & 7) * cpx + (blockIdx.x >> 3);
    const int mBase = (swz / NBX) * 256, nBase = (swz % NBX) * 256;

    const int NT = K >> 6;                                // K-tiles (even)

    const int stRow = w * 8 + (lane >> 3);
    const int stCol = (((lane & 7) ^ (lane >> 3)) << 3);
    const int rdsw  = (l16 & 7) << 3;

    const _Float16* Ag = A  + (size_t)mBase * K;
    const _Float16* Bg = Bm + (size_t)nBase * K;

    floatx4 acc[8][4];
    const floatx4 fz = {0.f, 0.f, 0.f, 0.f};
#pragma unroll
    for (int i = 0; i < 8; ++i)
#pragma unroll
        for (int j = 0; j < 4; ++j) acc[i][j] = fz;

    auto stA = [&](int tt, int h, _Float16* dst) {
#pragma unroll
        for (int r = 0; r < 2; ++r) {
            const int rb = h * 128 + r * 64;
            async16(Ag + (size_t)(rb + stRow) * K + tt * 64 + stCol,
                    dst + (size_t)(rb + w * 8) * 64);
        }
    };
    auto stB = [&](int tt, int h, _Float16* dst) {
#pragma unroll
        for (int r = 0; r < 2; ++r) {
            const int rb = h * 128 + r * 64;
            async16(Bg + (size_t)(rb + stRow) * K + tt * 64 + stCol,
                    dst + (size_t)(rb + w * 8) * 64);
        }
    };

    stA(0, 0, SM[0]); stA(0, 1, SM[0]);
    stB(0, 0, SM[2]); stB(0, 1, SM[2]);
    if (NT > 1) { stB(1, 0, SM[3]); stB(1, 1, SM[3]); }
    asm volatile("s_waitcnt vmcnt(4)" ::: "memory");
    __builtin_amdgcn_s_barrier();

    auto tile = [&](int t, _Float16* Ab, _Float16* Bb, _Float16* Ao) {
        half8 bf[4][2], af[2][2];
#pragma unroll
        for (int c = 0; c < 4; ++c) {
            const int brow = wc * 64 + c * 16 + l16;
#pragma unroll
            for (int s = 0; s < 2; ++s)
                bf[c][s] = *(const half8*)&Bb[(size_t)brow * 64 + ((s * 32 + quad * 8) ^ rdsw)];
        }
#pragma unroll
        for (int r = 0; r < 2; ++r) {
            const int arow = wr * 128 + r * 16 + l16;
#pragma unroll
            for (int s = 0; s < 2; ++s)
                af[r][s] = *(const half8*)&Ab[(size_t)arow * 64 + ((s * 32 + quad * 8) ^ rdsw)];
        }
        if (t + 1 < NT) stA(t + 1, 0, Ao);
        asm volatile("s_waitcnt lgkmcnt(8)");
        __builtin_amdgcn_s_barrier();
        asm volatile("s_waitcnt lgkmcnt(0)");
        __builtin_amdgcn_s_setprio(1);
#pragma unroll
        for (int s = 0; s < 2; ++s)
#pragma unroll
            for (int c = 0; c < 4; ++c) {
                acc[0][c] = __builtin_amdgcn_mfma_f32_16x16x32_f16(af[0][s], bf[c][s], acc[0][c], 0, 0, 0);
                acc[1][c] = __builtin_amdgcn_mfma_f32_16x16x32_f16(af[1][s], bf[c][s], acc[1][c], 0, 0, 0);
            }
        __builtin_amdgcn_s_setprio(0);
        __builtin_amdgcn_s_barrier();
#pragma unroll
        for (int p = 1; p < 4; ++p) {
#pragma unroll
            for (int r = 0; r < 2; ++r) {
                const int arow = wr * 128 + (2 * p + r) * 16 + l16;
#pragma unroll
                for (int s = 0; s < 2; ++s)
                    af[r][s] = *(const half8*)&Ab[(size_t)arow * 64 + ((s * 32 + quad * 8) ^ rdsw)];
            }
            if (p == 1)      { if (t + 1 < NT) stA(t + 1, 1, Ao); }
            else if (p == 2) { if (t + 2 < NT) stB(t + 2, 0, Bb); }
            else             { if (t + 2 < NT) stB(t + 2, 1, Bb); }
            __builtin_amdgcn_s_barrier();
            asm volatile("s_waitcnt lgkmcnt(0)");
            __builtin_amdgcn_s_setprio(1);
#pragma unroll
            for (int s = 0; s < 2; ++s)
#pragma unroll
                for (int c = 0; c < 4; ++c) {
                    acc[2 * p][c]     = __builtin_amdgcn_mfma_f32_16x16x32_f16(af[0][s], bf[c][s], acc[2 * p][c], 0, 0, 0);
                    acc[2 * p + 1][c] = __builtin_amdgcn_mfma_f32_16x16x32_f16(af[1][s], bf[c][s], acc[2 * p + 1][c], 0, 0, 0);
                }
            __builtin_amdgcn_s_setprio(0);
            if (p == 3) {
                if (t < NT - 2) asm volatile("s_waitcnt vmcnt(4)" ::: "memory");
                else            asm volatile("s_waitcnt vmcnt(0)" ::: "memory");
            }
            __builtin_amdgcn_s_barrier();
        }
    };

    for (int t = 0; t < NT; t += 2) {
        tile(t,     SM[0], SM[2], SM[1]);
        tile(t + 1, SM[1], SM[3], SM[0]);
    }

    // ---- epilogue: LDS-staged coalesced C-write ----
    __syncthreads();
    if (C_FP32) {
        float* TF = (float*)&SM[0][0];               // 128 x 256 fp32 = 128 KB
        float* Cf = (float*)Cv;
#pragma unroll
        for (int h = 0; h < 2; ++h) {
            if (h) __syncthreads();
            if (wr == h) {
#pragma unroll
                for (int fr = 0; fr < 8; ++fr)
#pragma unroll
                    for (int c = 0; c < 4; ++c)
#pragma unroll
                        for (int r = 0; r < 4; ++r)
                            TF[(size_t)(fr * 16 + quad * 4 + r) * 256 + wc * 64 + c * 16 + l16] = acc[fr][c][r];
            }
            __syncthreads();
#pragma unroll
            for (int i = 0; i < 16; ++i) {
                const int o = i * 2048 + tid * 4;
                const int row = o >> 8, col = o & 255;
                *(floatx4*)&Cf[(size_t)(mBase + h * 128 + row) * N + nBase + col] =
                    *(const floatx4*)&TF[o];
            }
        }
    } else {
        _Float16* T = &SM[0][0];                     // 256 x 256 fp16 = 128 KB
        _Float16* Ch = (_Float16*)Cv;
#pragma unroll
        for (int fr = 0; fr < 8; ++fr)
#pragma unroll
            for (int c = 0; c < 4; ++c)
#pragma unroll
                for (int r = 0; r < 4; ++r)
                    T[(size_t)(wr * 128 + fr * 16 + quad * 4 + r) * 256 + wc * 64 + c * 16 + l16] =
                        (_Float16)acc[fr][c][r];
        __syncthreads();
#pragma unroll
        for (int i = 0; i < 16; ++i) {
            const int o = i * 4096 + tid * 8;
            const int row = o >> 8, col = o & 255;
            *(half8*)&Ch[(size_t)(mBase + row) * N + nBase + col] = *(const half8*)&T[o];
        }
    }
}

// ---------------------------------------------------------------------------
// IN-PLACE RMSNorm (per 256-dim head vector) + RoPE for q/k, plain RMS for v.
// ---------------------------------------------------------------------------
__global__ __launch_bounds__(256) void rmsrope_inplace(
    _Float16* __restrict__ qkv,        // [4096][4096] fp16
    const float* __restrict__ cosT,    // [S][D] fp32
    const float* __restrict__ sinT,
    const float* __restrict__ qw,      // [D] fp32
    const float* __restrict__ kw)
{
    const int t = blockIdx.x;                // b*S + s
    const int s = t & (S_ - 1);
    const int tid = threadIdx.x, lane = tid & 63, w = tid >> 6;
    _Float16* row = qkv + (size_t)t * QKV_LD;
    const int d0 = lane * 2, d1 = 128 + lane * 2;

    floatx2 c0 = *(const floatx2*)(cosT + (size_t)s * D_ + d0);
    floatx2 c1 = *(const floatx2*)(cosT + (size_t)s * D_ + d1);
    floatx2 s0 = *(const floatx2*)(sinT + (size_t)s * D_ + d0);
    floatx2 s1 = *(const floatx2*)(sinT + (size_t)s * D_ + d1);
    floatx2 qw0 = *(const floatx2*)(qw + d0), qw1 = *(const floatx2*)(qw + d1);
    floatx2 kw0 = *(const floatx2*)(kw + d0), kw1 = *(const floatx2*)(kw + d1);

#pragma unroll
    for (int p = 0; p < 4; ++p) {
        const int v = w + p * 4;             // 0..15, wave-uniform
        _Float16* x = row + v * D_;
        float x0a = (float)x[d0], x0b = (float)x[d0 + 1];
        float x1a = (float)x[d1], x1b = (float)x[d1 + 1];
        float ss = x0a * x0a + x0b * x0b + x1a * x1a + x1b * x1b;
#pragma unroll
        for (int off = 32; off > 0; off >>= 1) ss += __shfl_xor(ss, off, 64);
        const float rinv = rsqrtf(ss * (1.0f / 256.0f) + 1e-6f);
        if (v < 8) {
            const float y0a = x0a * rinv * (1.f + qw0.x), y0b = x0b * rinv * (1.f + qw0.y);
            const float y1a = x1a * rinv * (1.f + qw1.x), y1b = x1b * rinv * (1.f + qw1.y);
            x[d0] = (_Float16)(y0a * c0.x - y1a * s0.x);
            x[d0 + 1] = (_Float16)(y0b * c0.y - y1b * s0.y);
            x[d1] = (_Float16)(y1a * c1.x + y0a * s1.x);
            x[d1 + 1] = (_Float16)(y1b * c1.y + y0b * s1.y);
        } else if (v < 12) {
            const float y0a = x0a * rinv * (1.f + kw0.x), y0b = x0b * rinv * (1.f + kw0.y);
            const float y1a = x1a * rinv * (1.f + kw1.x), y1b = x1b * rinv * (1.f + kw1.y);
            x[d0] = (_Float16)(y0a * c0.x - y1a * s0.x);
            x[d0 + 1] = (_Float16)(y0b * c0.y - y1b * s0.y);
            x[d1] = (_Float16)(y1a * c1.x + y0a * s1.x);
            x[d1 + 1] = (_Float16)(y1b * c1.y + y0b * s1.y);
        } else {
            x[d0] = (_Float16)(x0a * rinv);
            x[d0 + 1] = (_Float16)(x0b * rinv);
            x[d1] = (_Float16)(x1a * rinv);
            x[d1 + 1] = (_Float16)(x1b * rinv);
        }
    }
}

// ---------------------------------------------------------------------------
// Transpose V out of qkv: [b][s][3072+kvh*256+d] -> Vt[b][kvh][d][s]
// ---------------------------------------------------------------------------
__global__ __launch_bounds__(256) void transpose_v(
    const _Float16* __restrict__ qkv, _Float16* __restrict__ Vt)
{
    __shared__ _Float16 tile[64][66];
    const int s0 = blockIdx.x * 64;
    const int dd0 = blockIdx.y * 64;
    const int bk = blockIdx.z;               // b*NKV + kvh
    const int b = bk >> 2, kvh = bk & 3;
    const _Float16* src = qkv + (size_t)(b * S_) * QKV_LD + 3072 + kvh * D_;
    _Float16* dst = Vt + (size_t)bk * D_ * S_;
    const int tx = threadIdx.x & 63, ty = threadIdx.x >> 6;
    for (int r = ty; r < 64; r += 4)
        tile[r][tx] = src[(size_t)(s0 + r) * QKV_LD + dd0 + tx];
    __syncthreads();
    for (int r = ty; r < 64; r += 4)
        dst[(size_t)(dd0 + r) * S_ + s0 + tx] = tile[tx][r];
}

// ---------------------------------------------------------------------------
// Flash attention v3.5 (unchanged from R11): DPP reductions + interior mask
// skip + defer-max + LPT heavy-first job order + XCD clustering.
// ---------------------------------------------------------------------------
#define PS_STRIDE 40

__global__ __launch_bounds__(256, 2) void attn_kernel(
    const _Float16* __restrict__ qkv,  // [B*S][4096] fp16 (post rms+rope)
    const _Float16* __restrict__ Vt,   // [B][NKV][D][S] fp16
    _Float16* __restrict__ Oa)         // [B*S][NH*D] fp16
{
    __shared__ __align__(16) _Float16 Ks[2][32 * 256];   // 2 x 16 KB
    __shared__ __align__(16) _Float16 Vs[2][256 * 32];   // 2 x 16 KB
    __shared__ __align__(16) _Float16 Ps[4][16 * PS_STRIDE];

    const int idx = blockIdx.x;                   // 0..511
    const int xcd = idx & 7, pos = idx >> 3;      // pos 0..63
    const int b = xcd >> 2;
    const int h0 = (xcd * 2) & 7;
    int qt, h;
    if (pos < 32) { qt = 16 + (pos >> 1); h = h0 + (pos & 1); }
    else          { const int p = pos - 32; qt = 15 - (p >> 1); h = h0 + (p & 1); }
    const int qb = qt * 64;
    const int kvh = h >> 1;                       // repeat_interleave(2)

    const int tid = threadIdx.x, lane = tid & 63, w = tid >> 6;
    const int quad = lane >> 4, l16 = lane & 15;
    const int q0 = qb + w * 16;                   // wave's first query

    const _Float16* Qrow = qkv + ((size_t)(b * S_ + q0 + l16)) * QKV_LD + h * D_;
    half8 qf[8];
#pragma unroll
    for (int kst = 0; kst < 8; ++kst)
        qf[kst] = *(const half8*)(Qrow + kst * 32 + quad * 8);

    floatx4 o[16];
    const floatx4 fzero = {0.f, 0.f, 0.f, 0.f};
#pragma unroll
    for (int dt = 0; dt < 16; ++dt) o[dt] = fzero;
    float mrow[4] = {-50000.f, -50000.f, -50000.f, -50000.f};
    float lrow[4] = {0.f, 0.f, 0.f, 0.f};

    const _Float16* Kbase  = qkv + (size_t)(b * S_) * QKV_LD + 2048 + kvh * D_;
    const _Float16* Vtbase = Vt + (size_t)(b * NKV_ + kvh) * D_ * S_;
    const int kb_start = (qb >= SW_) ? qb - SW_ : 0;
    const int kb_end = qb + 32;  // inclusive

    auto stage = [&](int kb, int bufi) {
#pragma unroll
        for (int p = 0; p < 4; ++p) {
            const int keyl = w * 8 + p * 2 + (lane >> 5);     // 0..31
            const int g = ((lane & 31) - keyl) & 31;          // rotated source chunk
            async16(Kbase + (size_t)(kb + keyl) * QKV_LD + g * 8,
                    &Ks[bufi][(w * 8 + p * 2) * 256]);
        }
#pragma unroll
        for (int p = 0; p < 4; ++p) {
            const int drow = w * 64 + p * 16 + (lane >> 2);   // 0..255
            const int q = lane & 3;
            async16(Vtbase + (size_t)drow * S_ + kb + q * 8,
                    &Vs[bufi][(w * 64 + p * 16) * 32]);
        }
    };

    int buf = 0;
    stage(kb_start, 0);

    for (int kb = kb_start; kb <= kb_end; kb += 32) {
        __syncthreads();
        if (kb + 32 <= kb_end) stage(kb + 32, buf ^ 1);

        if ((kb <= q0 + 15) && (kb + 31 >= q0 - (SW_ - 1))) {
            floatx4 sacc[2];
            sacc[0] = fzero; sacc[1] = fzero;
            __builtin_amdgcn_s_setprio(1);
#pragma unroll
            for (int jt = 0; jt < 2; ++jt) {
                const int keyl = jt * 16 + l16;
#pragma unroll
                for (int kst = 0; kst < 8; ++kst) {
                    const int crot = (kst * 4 + quad + keyl) & 31;
                    half8 kf = *(const half8*)&Ks[buf][keyl * 256 + crot * 8];
                    sacc[jt] = __builtin_amdgcn_mfma_f32_16x16x32_f16(qf[kst], kf, sacc[jt], 0, 0, 0);
                }
            }
            __builtin_amdgcn_s_setprio(0);

            const int qq0 = q0 + quad * 4;
            const bool interior = (kb >= q0 - (SW_ - 16)) && (kb + 31 <= q0);
            float sval[2][4], tmax[4];
            if (interior) {
#pragma unroll
                for (int r = 0; r < 4; ++r)
                    tmax[r] = fmaxf(sacc[0][r], sacc[1][r]);
#pragma unroll
                for (int jt = 0; jt < 2; ++jt)
#pragma unroll
                    for (int r = 0; r < 4; ++r) sval[jt][r] = sacc[jt][r];
            } else {
#pragma unroll
                for (int r = 0; r < 4; ++r) tmax[r] = -1e30f;
#pragma unroll
                for (int jt = 0; jt < 2; ++jt) {
                    const int kg = kb + jt * 16 + l16;
#pragma unroll
                    for (int r = 0; r < 4; ++r) {
                        const int qg = qq0 + r;
                        const bool ok = (unsigned)(qg - kg) < (unsigned)SW_;
                        const float vv = ok ? sacc[jt][r] : -1e30f;
                        sval[jt][r] = vv;
                        tmax[r] = fmaxf(tmax[r], vv);
                    }
                }
            }
            float alpha[4];
            bool need = false;
#pragma unroll
            for (int r = 0; r < 4; ++r) {
                const float t = red16_max(tmax[r]);
                const float mold = mrow[r];
                const float mnew = (t > mold + 8.f) ? t : mold;
                alpha[r] = __expf(mold - mnew);
                need |= (mnew != mold);
                mrow[r] = mnew;
                lrow[r] *= alpha[r];
            }
            if (__any(need)) {
#pragma unroll
                for (int dt = 0; dt < 16; ++dt)
#pragma unroll
                    for (int r = 0; r < 4; ++r) o[dt][r] *= alpha[r];
            }
            float rsum[4] = {0.f, 0.f, 0.f, 0.f};
#pragma unroll
            for (int jt = 0; jt < 2; ++jt)
#pragma unroll
                for (int r = 0; r < 4; ++r) {
                    const float pv = __expf(sval[jt][r] - mrow[r]);
                    rsum[r] += pv;
                    Ps[w][(quad * 4 + r) * PS_STRIDE + jt * 16 + l16] = (_Float16)pv;
                }
#pragma unroll
            for (int r = 0; r < 4; ++r)
                lrow[r] += red16_sum(rsum[r]);

            half8 pa = *(const half8*)&Ps[w][l16 * PS_STRIDE + quad * 8];
            __builtin_amdgcn_s_setprio(1);
#pragma unroll
            for (int dt = 0; dt < 16; ++dt) {
                half8 vf = *(const half8*)&Vs[buf][(dt * 16 + l16) * 32 + quad * 8];
                o[dt] = __builtin_amdgcn_mfma_f32_16x16x32_f16(pa, vf, o[dt], 0, 0, 0);
            }
            __builtin_amdgcn_s_setprio(0);
        }
        buf ^= 1;
    }

    const int qrow = q0 + quad * 4;
#pragma unroll
    for (int r = 0; r < 4; ++r) {
        const float inv = (lrow[r] > 0.f) ? (1.0f / lrow[r]) : 0.f;
        _Float16* orow = Oa + ((size_t)(b * S_ + qrow + r)) * (NH_ * D_) + h * D_;
#pragma unroll
        for (int dt = 0; dt < 16; ++dt)
            orow[dt * 16 + l16] = (_Float16)(o[dt][r] * inv);
    }
}

// ---------------------------------------------------------------------------
extern "C" void kernel_launch(void* const* d_in, const int* in_sizes, int n_in,
                              void* d_out, int out_size, void* d_ws, size_t ws_size,
                              hipStream_t stream)
{
    (void)in_sizes; (void)n_in; (void)out_size; (void)ws_size;
    const float* hid  = (const float*)d_in[0];
    // d_in[1] = attention_mask (unused: analytic causal+window mask is exact)
    const float* cosT = (const float*)d_in[2];
    const float* sinT = (const float*)d_in[3];
    const float* Wq   = (const float*)d_in[4];
    const float* Wk   = (const float*)d_in[5];
    const float* Wv   = (const float*)d_in[6];
    const float* Wo   = (const float*)d_in[7];
    const float* qw   = (const float*)d_in[8];
    const float* kw   = (const float*)d_in[9];
    float* out = (float*)d_out;

    // workspace layout (bytes; ~111 MB total)
    char* ws = (char*)d_ws;
    _Float16* qkv  = (_Float16*)(ws);                      // 33,554,432  [4096][4096]
    _Float16* attn = (_Float16*)(ws + 33554432ull);        // 16,777,216  [4096][2048]
    _Float16* hidH = (_Float16*)(ws + 50331648ull);        // 20,971,520  [4096][2560]
    _Float16* wQKV = (_Float16*)(ws + 71303168ull);        // 20,971,520  [4096][2560]
    _Float16* woH  = (_Float16*)(ws + 92274688ull);        // 10,485,760  [2560][2048]
    _Float16* Vt   = (_Float16*)(ws + 102760448ull);       //  8,388,608  [B][NKV][D][S]

    // 0) all fp32 -> fp16 conversions in one launch
    conv_all<<<dim3(512, 5), 256, 0, stream>>>(
        hid, Wq, Wk, Wv, Wo,
        hidH, wQKV, wQKV + (size_t)2048 * 2560, wQKV + (size_t)3072 * 2560, woH);

    // 1) QKV projection (fp16 MFMA, 256^2 8-phase + staged C-write)
    gemm256<0><<<dim3(256), 512, 0, stream>>>(hidH, wQKV, qkv, 4096, 4096, 2560, 16);
    // 2) in-place RMSNorm + RoPE on qkv
    rmsrope_inplace<<<4096, 256, 0, stream>>>(qkv, cosT, sinT, qw, kw);
    // 3) V transpose -> Vt [b][kvh][d][s]
    transpose_v<<<dim3(32, 4, 8), 256, 0, stream>>>(qkv, Vt);
    // 4) flash attention v3.5 (DPP reductions + interior mask skip + LPT)
    attn_kernel<<<dim3(512), 256, 0, stream>>>(qkv, Vt, attn);
    // 5) output projection: fp16 [4096,2048] @ Wo^T -> fp32 out [4096][2560]
    gemm256<1><<<dim3(160), 512, 0, stream>>>(attn, woH, out, 4096, 2560, 2048, 10);
}

// Round 13
// 380.688 us; speedup vs baseline: 1.0146x; 1.0146x over previous
//
#include <hip/hip_runtime.h>

#define B_   2
#define S_   2048
#define H_   2560
#define NH_  8
#define NKV_ 4
#define D_   256
#define SW_  1024

// qkv row layout (fp16, stride 4096): [0,2048) Q heads, [2048,3072) K, [3072,4096) V
#define QKV_LD 4096

typedef __attribute__((ext_vector_type(8))) short    short8;
typedef __attribute__((ext_vector_type(8))) _Float16 half8;
typedef __attribute__((ext_vector_type(4))) _Float16 half4;
typedef __attribute__((ext_vector_type(4))) float    floatx4;
typedef __attribute__((ext_vector_type(2))) float    floatx2;

typedef unsigned int __attribute__((address_space(1))) as1_uint;
typedef unsigned int __attribute__((address_space(3))) as3_uint;

static __device__ __forceinline__ void async16(const void* g, void* l) {
    __builtin_amdgcn_global_load_lds((const as1_uint*)g, (as3_uint*)l, 16, 0, 0);
}

// 16-lane reductions via DPP row_ror (VALU-speed) instead of __shfl_xor
// (ds_bpermute). Commutative reduction: ror:{8,4,2,1} covers all 16 lanes.
static __device__ __forceinline__ float red16_max(float v) {
    int x;
    x = __builtin_amdgcn_update_dpp(0, __float_as_int(v), 0x128, 0xf, 0xf, true);
    v = fmaxf(v, __int_as_float(x));
    x = __builtin_amdgcn_update_dpp(0, __float_as_int(v), 0x124, 0xf, 0xf, true);
    v = fmaxf(v, __int_as_float(x));
    x = __builtin_amdgcn_update_dpp(0, __float_as_int(v), 0x122, 0xf, 0xf, true);
    v = fmaxf(v, __int_as_float(x));
    x = __builtin_amdgcn_update_dpp(0, __float_as_int(v), 0x121, 0xf, 0xf, true);
    v = fmaxf(v, __int_as_float(x));
    return v;
}
static __device__ __forceinline__ float red16_sum(float v) {
    int x;
    x = __builtin_amdgcn_update_dpp(0, __float_as_int(v), 0x128, 0xf, 0xf, true);
    v += __int_as_float(x);
    x = __builtin_amdgcn_update_dpp(0, __float_as_int(v), 0x124, 0xf, 0xf, true);
    v += __int_as_float(x);
    x = __builtin_amdgcn_update_dpp(0, __float_as_int(v), 0x122, 0xf, 0xf, true);
    v += __int_as_float(x);
    x = __builtin_amdgcn_update_dpp(0, __float_as_int(v), 0x121, 0xf, 0xf, true);
    v += __int_as_float(x);
    return v;
}

// ---------------------------------------------------------------------------
// Fused fp32 -> fp16 conversion for all 5 tensors (blockIdx.y selects tensor)
// ---------------------------------------------------------------------------
__global__ __launch_bounds__(256) void conv_all(
    const float* __restrict__ s0, const float* __restrict__ s1,
    const float* __restrict__ s2, const float* __restrict__ s3,
    const float* __restrict__ s4,
    _Float16* __restrict__ d0, _Float16* __restrict__ d1,
    _Float16* __restrict__ d2, _Float16* __restrict__ d3,
    _Float16* __restrict__ d4)
{
    const float* src; _Float16* dst; int n4;
    switch (blockIdx.y) {
        case 0:  src = s0; dst = d0; n4 = 4096 * 2560 / 4; break;   // hidden
        case 1:  src = s1; dst = d1; n4 = 2048 * 2560 / 4; break;   // Wq
        case 2:  src = s2; dst = d2; n4 = 1024 * 2560 / 4; break;   // Wk
        case 3:  src = s3; dst = d3; n4 = 1024 * 2560 / 4; break;   // Wv
        default: src = s4; dst = d4; n4 = 2560 * 2048 / 4; break;   // Wo
    }
    for (int i = blockIdx.x * 256 + threadIdx.x; i < n4; i += gridDim.x * 256) {
        floatx4 v = *(const floatx4*)(src + (size_t)i * 4);
        half4 h = { (_Float16)v.x, (_Float16)v.y, (_Float16)v.z, (_Float16)v.w };
        *(half4*)(dst + (size_t)i * 4) = h;
    }
}

// ---------------------------------------------------------------------------
// fp16 GEMM, 256x256 tile, BK=64, 8 waves (2Mx4N), 8-phase schedule (m201
// template). R13: epilogue reverted to R11's direct scattered store -- the
// R12 LDS-staged C-write regressed (+2.7us, +524K conflicts): the scattered
// stores were already hidden under the K-loop; extra LDS traffic hurt an
// LDS-saturated kernel.
// ---------------------------------------------------------------------------
template <int C_FP32>
__global__ __launch_bounds__(512, 2) void gemm256(
    const _Float16* __restrict__ A,    // [M][K]
    const _Float16* __restrict__ Bm,   // [N][K]
    void* __restrict__ Cv,             // [M][N]
    int M, int N, int K, int NBX)
{
    (void)M;
    __shared__ __align__(16) _Float16 As[2][256 * 64];   // 2 x 32 KB
    __shared__ __align__(16) _Float16 Bs[2][256 * 64];   // 2 x 32 KB

    const int tid  = threadIdx.x;
    const int lane = tid & 63, w = tid >> 6;
    const int wr = w >> 2, wc = w & 3;                   // 2 x 4 wave grid
    const int quad = lane >> 4, l16 = lane & 15;

    const int nwg = gridDim.x, cpx = nwg >> 3;
    const int swz = (blockIdx.x & 7) * cpx + (blockIdx.x >> 3);
    const int mBase = (swz / NBX) * 256, nBase = (swz % NBX) * 256;

    const int NT = K >> 6;                                // K-tiles (even)

    const int stRow = w * 8 + (lane >> 3);
    const int stCol = (((lane & 7) ^ (lane >> 3)) << 3);
    const int rdsw  = (l16 & 7) << 3;

    const _Float16* Ag = A  + (size_t)mBase * K;
    const _Float16* Bg = Bm + (size_t)nBase * K;

    floatx4 acc[8][4];
    const floatx4 fz = {0.f, 0.f, 0.f, 0.f};
#pragma unroll
    for (int i = 0; i < 8; ++i)
#pragma unroll
        for (int j = 0; j < 4; ++j) acc[i][j] = fz;

    auto stA = [&](int tt, int h, _Float16* dst) {
#pragma unroll
        for (int r = 0; r < 2; ++r) {
            const int rb = h * 128 + r * 64;
            async16(Ag + (size_t)(rb + stRow) * K + tt * 64 + stCol,
                    dst + (size_t)(rb + w * 8) * 64);
        }
    };
    auto stB = [&](int tt, int h, _Float16* dst) {
#pragma unroll
        for (int r = 0; r < 2; ++r) {
            const int rb = h * 128 + r * 64;
            async16(Bg + (size_t)(rb + stRow) * K + tt * 64 + stCol,
                    dst + (size_t)(rb + w * 8) * 64);
        }
    };

    stA(0, 0, &As[0][0]); stA(0, 1, &As[0][0]);
    stB(0, 0, &Bs[0][0]); stB(0, 1, &Bs[0][0]);
    if (NT > 1) { stB(1, 0, &Bs[1][0]); stB(1, 1, &Bs[1][0]); }
    asm volatile("s_waitcnt vmcnt(4)" ::: "memory");
    __builtin_amdgcn_s_barrier();

    auto tile = [&](int t, _Float16* Ab, _Float16* Bb, _Float16* Ao) {
        half8 bf[4][2], af[2][2];
#pragma unroll
        for (int c = 0; c < 4; ++c) {
            const int brow = wc * 64 + c * 16 + l16;
#pragma unroll
            for (int s = 0; s < 2; ++s)
                bf[c][s] = *(const half8*)&Bb[(size_t)brow * 64 + ((s * 32 + quad * 8) ^ rdsw)];
        }
#pragma unroll
        for (int r = 0; r < 2; ++r) {
            const int arow = wr * 128 + r * 16 + l16;
#pragma unroll
            for (int s = 0; s < 2; ++s)
                af[r][s] = *(const half8*)&Ab[(size_t)arow * 64 + ((s * 32 + quad * 8) ^ rdsw)];
        }
        if (t + 1 < NT) stA(t + 1, 0, Ao);
        asm volatile("s_waitcnt lgkmcnt(8)");
        __builtin_amdgcn_s_barrier();
        asm volatile("s_waitcnt lgkmcnt(0)");
        __builtin_amdgcn_s_setprio(1);
#pragma unroll
        for (int s = 0; s < 2; ++s)
#pragma unroll
            for (int c = 0; c < 4; ++c) {
                acc[0][c] = __builtin_amdgcn_mfma_f32_16x16x32_f16(af[0][s], bf[c][s], acc[0][c], 0, 0, 0);
                acc[1][c] = __builtin_amdgcn_mfma_f32_16x16x32_f16(af[1][s], bf[c][s], acc[1][c], 0, 0, 0);
            }
        __builtin_amdgcn_s_setprio(0);
        __builtin_amdgcn_s_barrier();
#pragma unroll
        for (int p = 1; p < 4; ++p) {
#pragma unroll
            for (int r = 0; r < 2; ++r) {
                const int arow = wr * 128 + (2 * p + r) * 16 + l16;
#pragma unroll
                for (int s = 0; s < 2; ++s)
                    af[r][s] = *(const half8*)&Ab[(size_t)arow * 64 + ((s * 32 + quad * 8) ^ rdsw)];
            }
            if (p == 1)      { if (t + 1 < NT) stA(t + 1, 1, Ao); }
            else if (p == 2) { if (t + 2 < NT) stB(t + 2, 0, Bb); }
            else             { if (t + 2 < NT) stB(t + 2, 1, Bb); }
            __builtin_amdgcn_s_barrier();
            asm volatile("s_waitcnt lgkmcnt(0)");
            __builtin_amdgcn_s_setprio(1);
#pragma unroll
            for (int s = 0; s < 2; ++s)
#pragma unroll
                for (int c = 0; c < 4; ++c) {
                    acc[2 * p][c]     = __builtin_amdgcn_mfma_f32_16x16x32_f16(af[0][s], bf[c][s], acc[2 * p][c], 0, 0, 0);
                    acc[2 * p + 1][c] = __builtin_amdgcn_mfma_f32_16x16x32_f16(af[1][s], bf[c][s], acc[2 * p + 1][c], 0, 0, 0);
                }
            __builtin_amdgcn_s_setprio(0);
            if (p == 3) {
                if (t < NT - 2) asm volatile("s_waitcnt vmcnt(4)" ::: "memory");
                else            asm volatile("s_waitcnt vmcnt(0)" ::: "memory");
            }
            __builtin_amdgcn_s_barrier();
        }
    };

    for (int t = 0; t < NT; t += 2) {
        tile(t,     &As[0][0], &Bs[0][0], &As[1][0]);
        tile(t + 1, &As[1][0], &Bs[1][0], &As[0][0]);
    }

    // epilogue: direct scattered store (R11 form; C/D layout col=lane&15,
    // row=quad*4+reg, m89-verified)
#pragma unroll
    for (int fr = 0; fr < 8; ++fr) {
        const int row0 = mBase + wr * 128 + fr * 16 + quad * 4;
#pragma unroll
        for (int c = 0; c < 4; ++c) {
            const int col = nBase + wc * 64 + c * 16 + l16;
#pragma unroll
            for (int r = 0; r < 4; ++r) {
                const size_t idx = (size_t)(row0 + r) * N + col;
                if (C_FP32) ((float*)Cv)[idx] = acc[fr][c][r];
                else        ((_Float16*)Cv)[idx] = (_Float16)acc[fr][c][r];
            }
        }
    }
}

// ---------------------------------------------------------------------------
// IN-PLACE RMSNorm + RoPE for q/k ONLY (R13: V heads dropped -- V is
// normalized inside transpose_rms_v now; qkv's V region is never read
// again). p loop 0..2 -> vectors 0..11 (8 q + 4 k).
// ---------------------------------------------------------------------------
__global__ __launch_bounds__(256) void rmsrope_inplace(
    _Float16* __restrict__ qkv,        // [4096][4096] fp16
    const float* __restrict__ cosT,    // [S][D] fp32
    const float* __restrict__ sinT,
    const float* __restrict__ qw,      // [D] fp32
    const float* __restrict__ kw)
{
    const int t = blockIdx.x;                // b*S + s
    const int s = t & (S_ - 1);
    const int tid = threadIdx.x, lane = tid & 63, w = tid >> 6;
    _Float16* row = qkv + (size_t)t * QKV_LD;
    const int d0 = lane * 2, d1 = 128 + lane * 2;

    floatx2 c0 = *(const floatx2*)(cosT + (size_t)s * D_ + d0);
    floatx2 c1 = *(const floatx2*)(cosT + (size_t)s * D_ + d1);
    floatx2 s0 = *(const floatx2*)(sinT + (size_t)s * D_ + d0);
    floatx2 s1 = *(const floatx2*)(sinT + (size_t)s * D_ + d1);
    floatx2 qw0 = *(const floatx2*)(qw + d0), qw1 = *(const floatx2*)(qw + d1);
    floatx2 kw0 = *(const floatx2*)(kw + d0), kw1 = *(const floatx2*)(kw + d1);

#pragma unroll
    for (int p = 0; p < 3; ++p) {
        const int v = w + p * 4;             // 0..11, wave-uniform
        _Float16* x = row + v * D_;
        float x0a = (float)x[d0], x0b = (float)x[d0 + 1];
        float x1a = (float)x[d1], x1b = (float)x[d1 + 1];
        float ss = x0a * x0a + x0b * x0b + x1a * x1a + x1b * x1b;
#pragma unroll
        for (int off = 32; off > 0; off >>= 1) ss += __shfl_xor(ss, off, 64);
        const float rinv = rsqrtf(ss * (1.0f / 256.0f) + 1e-6f);
        if (v < 8) {
            const float y0a = x0a * rinv * (1.f + qw0.x), y0b = x0b * rinv * (1.f + qw0.y);
            const float y1a = x1a * rinv * (1.f + qw1.x), y1b = x1b * rinv * (1.f + qw1.y);
            x[d0] = (_Float16)(y0a * c0.x - y1a * s0.x);
            x[d0 + 1] = (_Float16)(y0b * c0.y - y1b * s0.y);
            x[d1] = (_Float16)(y1a * c1.x + y0a * s1.x);
            x[d1 + 1] = (_Float16)(y1b * c1.y + y0b * s1.y);
        } else {
            const float y0a = x0a * rinv * (1.f + kw0.x), y0b = x0b * rinv * (1.f + kw0.y);
            const float y1a = x1a * rinv * (1.f + kw1.x), y1b = x1b * rinv * (1.f + kw1.y);
            x[d0] = (_Float16)(y0a * c0.x - y1a * s0.x);
            x[d0 + 1] = (_Float16)(y0b * c0.y - y1b * s0.y);
            x[d1] = (_Float16)(y1a * c1.x + y0a * s1.x);
            x[d1 + 1] = (_Float16)(y1b * c1.y + y0b * s1.y);
        }
    }
}

// ---------------------------------------------------------------------------
// V transpose WITH fused RMSNorm (R13): reads raw gemm V output from qkv,
// computes per-token rsqrt(mean(x^2)+eps), normalizes, writes Vt[b][kvh][d][s].
// Block: 256 thr, grid (64 token-tiles, 4 kvh). Phase 1: thread (r=tid>>2,
// c4=tid&3) loads its 64-elem chunk (4 consecutive tids = 512B contiguous),
// partial ssq + LDS combine, normalize, write TRANSPOSED into Lt with XOR
// column swizzle (col = r ^ ((d&7)<<3), rule-21 both-sides). Phase 2:
// thread d reads its 64-token row (half8, conflict-free: XOR spreads the
// 128B-stride rows across all 32 banks), stores 128B contiguous to Vt.
// ---------------------------------------------------------------------------
__global__ __launch_bounds__(256) void transpose_rms_v(
    const _Float16* __restrict__ qkv, _Float16* __restrict__ Vt)
{
    __shared__ __align__(16) _Float16 Lt[256][64];   // 32 KB, XOR-swizzled cols
    __shared__ float ssq[64][4];
    const int ti = blockIdx.x;              // 0..63 token tile (64 tokens)
    const int kvh = blockIdx.y;             // 0..3
    const int t0 = ti * 64;                 // linear token = b*S + s
    const int b = t0 >> 11;
    const int s0 = t0 & (S_ - 1);
    const int tid = threadIdx.x;
    const int r = tid >> 2, c4 = tid & 3;

    // phase 1: load + sum(x^2) partials
    const _Float16* src = qkv + (size_t)(t0 + r) * QKV_LD + 3072 + kvh * D_ + c4 * 64;
    half8 xv[8];
    float ss = 0.f;
#pragma unroll
    for (int i = 0; i < 8; ++i) {
        xv[i] = *(const half8*)(src + i * 8);
#pragma unroll
        for (int j = 0; j < 8; ++j) { const float f = (float)xv[i][j]; ss += f * f; }
    }
    ssq[r][c4] = ss;
    __syncthreads();
    const float tot = ssq[r][0] + ssq[r][1] + ssq[r][2] + ssq[r][3];
    const float rinv = rsqrtf(tot * (1.0f / 256.0f) + 1e-6f);
    // normalize + transposed LDS write (d&7 == j for all lanes -> uniform XOR)
#pragma unroll
    for (int i = 0; i < 8; ++i)
#pragma unroll
        for (int j = 0; j < 8; ++j) {
            const int d = c4 * 64 + i * 8 + j;
            Lt[d][r ^ ((d & 7) << 3)] = (_Float16)((float)xv[i][j] * rinv);
        }
    __syncthreads();

    // phase 2: coalesced Vt store (thread = d row)
    const int dd = tid;
    _Float16* dst = Vt + ((size_t)(b * NKV_ + kvh) * D_ + dd) * S_ + s0;
    const int xr = (dd & 7) << 3;
#pragma unroll
    for (int i = 0; i < 8; ++i)
        *(half8*)(dst + ((i * 8) ^ xr)) = *(const half8*)&Lt[dd][i * 8];
}

// ---------------------------------------------------------------------------
// Flash attention v3.5 (unchanged from R11): DPP reductions + interior mask
// skip + defer-max + LPT heavy-first job order + XCD clustering.
// ---------------------------------------------------------------------------
#define PS_STRIDE 40

__global__ __launch_bounds__(256, 2) void attn_kernel(
    const _Float16* __restrict__ qkv,  // [B*S][4096] fp16 (post rms+rope)
    const _Float16* __restrict__ Vt,   // [B][NKV][D][S] fp16
    _Float16* __restrict__ Oa)         // [B*S][NH*D] fp16
{
    __shared__ __align__(16) _Float16 Ks[2][32 * 256];   // 2 x 16 KB
    __shared__ __align__(16) _Float16 Vs[2][256 * 32];   // 2 x 16 KB
    __shared__ __align__(16) _Float16 Ps[4][16 * PS_STRIDE];

    const int idx = blockIdx.x;                   // 0..511
    const int xcd = idx & 7, pos = idx >> 3;      // pos 0..63
    const int b = xcd >> 2;
    const int h0 = (xcd * 2) & 7;
    int qt, h;
    if (pos < 32) { qt = 16 + (pos >> 1); h = h0 + (pos & 1); }
    else          { const int p = pos - 32; qt = 15 - (p >> 1); h = h0 + (p & 1); }
    const int qb = qt * 64;
    const int kvh = h >> 1;                       // repeat_interleave(2)

    const int tid = threadIdx.x, lane = tid & 63, w = tid >> 6;
    const int quad = lane >> 4, l16 = lane & 15;
    const int q0 = qb + w * 16;                   // wave's first query

    const _Float16* Qrow = qkv + ((size_t)(b * S_ + q0 + l16)) * QKV_LD + h * D_;
    half8 qf[8];
#pragma unroll
    for (int kst = 0; kst < 8; ++kst)
        qf[kst] = *(const half8*)(Qrow + kst * 32 + quad * 8);

    floatx4 o[16];
    const floatx4 fzero = {0.f, 0.f, 0.f, 0.f};
#pragma unroll
    for (int dt = 0; dt < 16; ++dt) o[dt] = fzero;
    float mrow[4] = {-50000.f, -50000.f, -50000.f, -50000.f};
    float lrow[4] = {0.f, 0.f, 0.f, 0.f};

    const _Float16* Kbase  = qkv + (size_t)(b * S_) * QKV_LD + 2048 + kvh * D_;
    const _Float16* Vtbase = Vt + (size_t)(b * NKV_ + kvh) * D_ * S_;
    const int kb_start = (qb >= SW_) ? qb - SW_ : 0;
    const int kb_end = qb + 32;  // inclusive

    auto stage = [&](int kb, int bufi) {
#pragma unroll
        for (int p = 0; p < 4; ++p) {
            const int keyl = w * 8 + p * 2 + (lane >> 5);     // 0..31
            const int g = ((lane & 31) - keyl) & 31;          // rotated source chunk
            async16(Kbase + (size_t)(kb + keyl) * QKV_LD + g * 8,
                    &Ks[bufi][(w * 8 + p * 2) * 256]);
        }
#pragma unroll
        for (int p = 0; p < 4; ++p) {
            const int drow = w * 64 + p * 16 + (lane >> 2);   // 0..255
            const int q = lane & 3;
            async16(Vtbase + (size_t)drow * S_ + kb + q * 8,
                    &Vs[bufi][(w * 64 + p * 16) * 32]);
        }
    };

    int buf = 0;
    stage(kb_start, 0);

    for (int kb = kb_start; kb <= kb_end; kb += 32) {
        __syncthreads();
        if (kb + 32 <= kb_end) stage(kb + 32, buf ^ 1);

        if ((kb <= q0 + 15) && (kb + 31 >= q0 - (SW_ - 1))) {
            floatx4 sacc[2];
            sacc[0] = fzero; sacc[1] = fzero;
            __builtin_amdgcn_s_setprio(1);
#pragma unroll
            for (int jt = 0; jt < 2; ++jt) {
                const int keyl = jt * 16 + l16;
#pragma unroll
                for (int kst = 0; kst < 8; ++kst) {
                    const int crot = (kst * 4 + quad + keyl) & 31;
                    half8 kf = *(const half8*)&Ks[buf][keyl * 256 + crot * 8];
                    sacc[jt] = __builtin_amdgcn_mfma_f32_16x16x32_f16(qf[kst], kf, sacc[jt], 0, 0, 0);
                }
            }
            __builtin_amdgcn_s_setprio(0);

            const int qq0 = q0 + quad * 4;
            const bool interior = (kb >= q0 - (SW_ - 16)) && (kb + 31 <= q0);
            float sval[2][4], tmax[4];
            if (interior) {
#pragma unroll
                for (int r = 0; r < 4; ++r)
                    tmax[r] = fmaxf(sacc[0][r], sacc[1][r]);
#pragma unroll
                for (int jt = 0; jt < 2; ++jt)
#pragma unroll
                    for (int r = 0; r < 4; ++r) sval[jt][r] = sacc[jt][r];
            } else {
#pragma unroll
                for (int r = 0; r < 4; ++r) tmax[r] = -1e30f;
#pragma unroll
                for (int jt = 0; jt < 2; ++jt) {
                    const int kg = kb + jt * 16 + l16;
#pragma unroll
                    for (int r = 0; r < 4; ++r) {
                        const int qg = qq0 + r;
                        const bool ok = (unsigned)(qg - kg) < (unsigned)SW_;
                        const float vv = ok ? sacc[jt][r] : -1e30f;
                        sval[jt][r] = vv;
                        tmax[r] = fmaxf(tmax[r], vv);
                    }
                }
            }
            float alpha[4];
            bool need = false;
#pragma unroll
            for (int r = 0; r < 4; ++r) {
                const float t = red16_max(tmax[r]);
                const float mold = mrow[r];
                const float mnew = (t > mold + 8.f) ? t : mold;
                alpha[r] = __expf(mold - mnew);
                need |= (mnew != mold);
                mrow[r] = mnew;
                lrow[r] *= alpha[r];
            }
            if (__any(need)) {
#pragma unroll
                for (int dt = 0; dt < 16; ++dt)
#pragma unroll
                    for (int r = 0; r < 4; ++r) o[dt][r] *= alpha[r];
            }
            float rsum[4] = {0.f, 0.f, 0.f, 0.f};
#pragma unroll
            for (int jt = 0; jt < 2; ++jt)
#pragma unroll
                for (int r = 0; r < 4; ++r) {
                    const float pv = __expf(sval[jt][r] - mrow[r]);
                    rsum[r] += pv;
                    Ps[w][(quad * 4 + r) * PS_STRIDE + jt * 16 + l16] = (_Float16)pv;
                }
#pragma unroll
            for (int r = 0; r < 4; ++r)
                lrow[r] += red16_sum(rsum[r]);

            half8 pa = *(const half8*)&Ps[w][l16 * PS_STRIDE + quad * 8];
            __builtin_amdgcn_s_setprio(1);
#pragma unroll
            for (int dt = 0; dt < 16; ++dt) {
                half8 vf = *(const half8*)&Vs[buf][(dt * 16 + l16) * 32 + quad * 8];
                o[dt] = __builtin_amdgcn_mfma_f32_16x16x32_f16(pa, vf, o[dt], 0, 0, 0);
            }
            __builtin_amdgcn_s_setprio(0);
        }
        buf ^= 1;
    }

    const int qrow = q0 + quad * 4;
#pragma unroll
    for (int r = 0; r < 4; ++r) {
        const float inv = (lrow[r] > 0.f) ? (1.0f / lrow[r]) : 0.f;
        _Float16* orow = Oa + ((size_t)(b * S_ + qrow + r)) * (NH_ * D_) + h * D_;
#pragma unroll
        for (int dt = 0; dt < 16; ++dt)
            orow[dt * 16 + l16] = (_Float16)(o[dt][r] * inv);
    }
}

// ---------------------------------------------------------------------------
extern "C" void kernel_launch(void* const* d_in, const int* in_sizes, int n_in,
                              void* d_out, int out_size, void* d_ws, size_t ws_size,
                              hipStream_t stream)
{
    (void)in_sizes; (void)n_in; (void)out_size; (void)ws_size;
    const float* hid  = (const float*)d_in[0];
    // d_in[1] = attention_mask (unused: analytic causal+window mask is exact)
    const float* cosT = (const float*)d_in[2];
    const float* sinT = (const float*)d_in[3];
    const float* Wq   = (const float*)d_in[4];
    const float* Wk   = (const float*)d_in[5];
    const float* Wv   = (const float*)d_in[6];
    const float* Wo   = (const float*)d_in[7];
    const float* qw   = (const float*)d_in[8];
    const float* kw   = (const float*)d_in[9];
    float* out = (float*)d_out;

    // workspace layout (bytes; ~111 MB total)
    char* ws = (char*)d_ws;
    _Float16* qkv  = (_Float16*)(ws);                      // 33,554,432  [4096][4096]
    _Float16* attn = (_Float16*)(ws + 33554432ull);        // 16,777,216  [4096][2048]
    _Float16* hidH = (_Float16*)(ws + 50331648ull);        // 20,971,520  [4096][2560]
    _Float16* wQKV = (_Float16*)(ws + 71303168ull);        // 20,971,520  [4096][2560]
    _Float16* woH  = (_Float16*)(ws + 92274688ull);        // 10,485,760  [2560][2048]
    _Float16* Vt   = (_Float16*)(ws + 102760448ull);       //  8,388,608  [B][NKV][D][S]

    // 0) all fp32 -> fp16 conversions in one launch
    conv_all<<<dim3(512, 5), 256, 0, stream>>>(
        hid, Wq, Wk, Wv, Wo,
        hidH, wQKV, wQKV + (size_t)2048 * 2560, wQKV + (size_t)3072 * 2560, woH);

    // 1) QKV projection (fp16 MFMA, 256^2 8-phase): -> fp16 [4096][4096]
    gemm256<0><<<dim3(256), 512, 0, stream>>>(hidH, wQKV, qkv, 4096, 4096, 2560, 16);
    // 2) V transpose + fused V-RMSNorm -> Vt (reads raw gemm output)
    transpose_rms_v<<<dim3(64, 4), 256, 0, stream>>>(qkv, Vt);
    // 3) in-place RMSNorm + RoPE on q/k heads only
    rmsrope_inplace<<<4096, 256, 0, stream>>>(qkv, cosT, sinT, qw, kw);
    // 4) flash attention v3.5 (DPP reductions + interior mask skip + LPT)
    attn_kernel<<<dim3(512), 256, 0, stream>>>(qkv, Vt, attn);
    // 5) output projection: fp16 [4096,2048] @ Wo^T -> fp32 out [4096][2560]
    gemm256<1><<<dim3(160), 512, 0, stream>>>(attn, woH, out, 4096, 2560, 2048, 10);
}

// Round 14
// 378.182 us; speedup vs baseline: 1.0213x; 1.0066x over previous
//
#include <hip/hip_runtime.h>

#define B_   2
#define S_   2048
#define H_   2560
#define NH_  8
#define NKV_ 4
#define D_   256
#define SW_  1024

// qkv row layout (fp16, stride 4096): [0,2048) Q heads, [2048,3072) K, [3072,4096) V
#define QKV_LD 4096

typedef __attribute__((ext_vector_type(8))) short    short8;
typedef __attribute__((ext_vector_type(8))) _Float16 half8;
typedef __attribute__((ext_vector_type(4))) _Float16 half4;
typedef __attribute__((ext_vector_type(4))) float    floatx4;
typedef __attribute__((ext_vector_type(2))) float    floatx2;

typedef unsigned int __attribute__((address_space(1))) as1_uint;
typedef unsigned int __attribute__((address_space(3))) as3_uint;

static __device__ __forceinline__ void async16(const void* g, void* l) {
    __builtin_amdgcn_global_load_lds((const as1_uint*)g, (as3_uint*)l, 16, 0, 0);
}

// 16-lane reductions via DPP row_ror (VALU-speed) instead of __shfl_xor
// (ds_bpermute). Commutative reduction: ror:{8,4,2,1} covers all 16 lanes.
static __device__ __forceinline__ float red16_max(float v) {
    int x;
    x = __builtin_amdgcn_update_dpp(0, __float_as_int(v), 0x128, 0xf, 0xf, true);
    v = fmaxf(v, __int_as_float(x));
    x = __builtin_amdgcn_update_dpp(0, __float_as_int(v), 0x124, 0xf, 0xf, true);
    v = fmaxf(v, __int_as_float(x));
    x = __builtin_amdgcn_update_dpp(0, __float_as_int(v), 0x122, 0xf, 0xf, true);
    v = fmaxf(v, __int_as_float(x));
    x = __builtin_amdgcn_update_dpp(0, __float_as_int(v), 0x121, 0xf, 0xf, true);
    v = fmaxf(v, __int_as_float(x));
    return v;
}
static __device__ __forceinline__ float red16_sum(float v) {
    int x;
    x = __builtin_amdgcn_update_dpp(0, __float_as_int(v), 0x128, 0xf, 0xf, true);
    v += __int_as_float(x);
    x = __builtin_amdgcn_update_dpp(0, __float_as_int(v), 0x124, 0xf, 0xf, true);
    v += __int_as_float(x);
    x = __builtin_amdgcn_update_dpp(0, __float_as_int(v), 0x122, 0xf, 0xf, true);
    v += __int_as_float(x);
    x = __builtin_amdgcn_update_dpp(0, __float_as_int(v), 0x121, 0xf, 0xf, true);
    v += __int_as_float(x);
    return v;
}

// ---------------------------------------------------------------------------
// Fused fp32 -> fp16 conversion for all 5 tensors (blockIdx.y selects tensor)
// ---------------------------------------------------------------------------
__global__ __launch_bounds__(256) void conv_all(
    const float* __restrict__ s0, const float* __restrict__ s1,
    const float* __restrict__ s2, const float* __restrict__ s3,
    const float* __restrict__ s4,
    _Float16* __restrict__ d0, _Float16* __restrict__ d1,
    _Float16* __restrict__ d2, _Float16* __restrict__ d3,
    _Float16* __restrict__ d4)
{
    const float* src; _Float16* dst; int n4;
    switch (blockIdx.y) {
        case 0:  src = s0; dst = d0; n4 = 4096 * 2560 / 4; break;   // hidden
        case 1:  src = s1; dst = d1; n4 = 2048 * 2560 / 4; break;   // Wq
        case 2:  src = s2; dst = d2; n4 = 1024 * 2560 / 4; break;   // Wk
        case 3:  src = s3; dst = d3; n4 = 1024 * 2560 / 4; break;   // Wv
        default: src = s4; dst = d4; n4 = 2560 * 2048 / 4; break;   // Wo
    }
    for (int i = blockIdx.x * 256 + threadIdx.x; i < n4; i += gridDim.x * 256) {
        floatx4 v = *(const floatx4*)(src + (size_t)i * 4);
        half4 h = { (_Float16)v.x, (_Float16)v.y, (_Float16)v.z, (_Float16)v.w };
        *(half4*)(dst + (size_t)i * 4) = h;
    }
}

// ---------------------------------------------------------------------------
// fp16 GEMM, 256x256 tile, BK=64, 8 waves (2Mx4N), 8-phase schedule (m201
// template). Used for QKV (grid 256 = 1 block/CU, full chip).
// ---------------------------------------------------------------------------
template <int C_FP32>
__global__ __launch_bounds__(512, 2) void gemm256(
    const _Float16* __restrict__ A,    // [M][K]
    const _Float16* __restrict__ Bm,   // [N][K]
    void* __restrict__ Cv,             // [M][N]
    int M, int N, int K, int NBX)
{
    (void)M;
    __shared__ __align__(16) _Float16 As[2][256 * 64];   // 2 x 32 KB
    __shared__ __align__(16) _Float16 Bs[2][256 * 64];   // 2 x 32 KB

    const int tid  = threadIdx.x;
    const int lane = tid & 63, w = tid >> 6;
    const int wr = w >> 2, wc = w & 3;                   // 2 x 4 wave grid
    const int quad = lane >> 4, l16 = lane & 15;

    const int nwg = gridDim.x, cpx = nwg >> 3;
    const int swz = (blockIdx.x & 7) * cpx + (blockIdx.x >> 3);
    const int mBase = (swz / NBX) * 256, nBase = (swz % NBX) * 256;

    const int NT = K >> 6;                                // K-tiles (even)

    const int stRow = w * 8 + (lane >> 3);
    const int stCol = (((lane & 7) ^ (lane >> 3)) << 3);
    const int rdsw  = (l16 & 7) << 3;

    const _Float16* Ag = A  + (size_t)mBase * K;
    const _Float16* Bg = Bm + (size_t)nBase * K;

    floatx4 acc[8][4];
    const floatx4 fz = {0.f, 0.f, 0.f, 0.f};
#pragma unroll
    for (int i = 0; i < 8; ++i)
#pragma unroll
        for (int j = 0; j < 4; ++j) acc[i][j] = fz;

    auto stA = [&](int tt, int h, _Float16* dst) {
#pragma unroll
        for (int r = 0; r < 2; ++r) {
            const int rb = h * 128 + r * 64;
            async16(Ag + (size_t)(rb + stRow) * K + tt * 64 + stCol,
                    dst + (size_t)(rb + w * 8) * 64);
        }
    };
    auto stB = [&](int tt, int h, _Float16* dst) {
#pragma unroll
        for (int r = 0; r < 2; ++r) {
            const int rb = h * 128 + r * 64;
            async16(Bg + (size_t)(rb + stRow) * K + tt * 64 + stCol,
                    dst + (size_t)(rb + w * 8) * 64);
        }
    };

    stA(0, 0, &As[0][0]); stA(0, 1, &As[0][0]);
    stB(0, 0, &Bs[0][0]); stB(0, 1, &Bs[0][0]);
    if (NT > 1) { stB(1, 0, &Bs[1][0]); stB(1, 1, &Bs[1][0]); }
    asm volatile("s_waitcnt vmcnt(4)" ::: "memory");
    __builtin_amdgcn_s_barrier();

    auto tile = [&](int t, _Float16* Ab, _Float16* Bb, _Float16* Ao) {
        half8 bf[4][2], af[2][2];
#pragma unroll
        for (int c = 0; c < 4; ++c) {
            const int brow = wc * 64 + c * 16 + l16;
#pragma unroll
            for (int s = 0; s < 2; ++s)
                bf[c][s] = *(const half8*)&Bb[(size_t)brow * 64 + ((s * 32 + quad * 8) ^ rdsw)];
        }
#pragma unroll
        for (int r = 0; r < 2; ++r) {
            const int arow = wr * 128 + r * 16 + l16;
#pragma unroll
            for (int s = 0; s < 2; ++s)
                af[r][s] = *(const half8*)&Ab[(size_t)arow * 64 + ((s * 32 + quad * 8) ^ rdsw)];
        }
        if (t + 1 < NT) stA(t + 1, 0, Ao);
        asm volatile("s_waitcnt lgkmcnt(8)");
        __builtin_amdgcn_s_barrier();
        asm volatile("s_waitcnt lgkmcnt(0)");
        __builtin_amdgcn_s_setprio(1);
#pragma unroll
        for (int s = 0; s < 2; ++s)
#pragma unroll
            for (int c = 0; c < 4; ++c) {
                acc[0][c] = __builtin_amdgcn_mfma_f32_16x16x32_f16(af[0][s], bf[c][s], acc[0][c], 0, 0, 0);
                acc[1][c] = __builtin_amdgcn_mfma_f32_16x16x32_f16(af[1][s], bf[c][s], acc[1][c], 0, 0, 0);
            }
        __builtin_amdgcn_s_setprio(0);
        __builtin_amdgcn_s_barrier();
#pragma unroll
        for (int p = 1; p < 4; ++p) {
#pragma unroll
            for (int r = 0; r < 2; ++r) {
                const int arow = wr * 128 + (2 * p + r) * 16 + l16;
#pragma unroll
                for (int s = 0; s < 2; ++s)
                    af[r][s] = *(const half8*)&Ab[(size_t)arow * 64 + ((s * 32 + quad * 8) ^ rdsw)];
            }
            if (p == 1)      { if (t + 1 < NT) stA(t + 1, 1, Ao); }
            else if (p == 2) { if (t + 2 < NT) stB(t + 2, 0, Bb); }
            else             { if (t + 2 < NT) stB(t + 2, 1, Bb); }
            __builtin_amdgcn_s_barrier();
            asm volatile("s_waitcnt lgkmcnt(0)");
            __builtin_amdgcn_s_setprio(1);
#pragma unroll
            for (int s = 0; s < 2; ++s)
#pragma unroll
                for (int c = 0; c < 4; ++c) {
                    acc[2 * p][c]     = __builtin_amdgcn_mfma_f32_16x16x32_f16(af[0][s], bf[c][s], acc[2 * p][c], 0, 0, 0);
                    acc[2 * p + 1][c] = __builtin_amdgcn_mfma_f32_16x16x32_f16(af[1][s], bf[c][s], acc[2 * p + 1][c], 0, 0, 0);
                }
            __builtin_amdgcn_s_setprio(0);
            if (p == 3) {
                if (t < NT - 2) asm volatile("s_waitcnt vmcnt(4)" ::: "memory");
                else            asm volatile("s_waitcnt vmcnt(0)" ::: "memory");
            }
            __builtin_amdgcn_s_barrier();
        }
    };

    for (int t = 0; t < NT; t += 2) {
        tile(t,     &As[0][0], &Bs[0][0], &As[1][0]);
        tile(t + 1, &As[1][0], &Bs[1][0], &As[0][0]);
    }

    // epilogue: direct scattered store (C/D layout col=lane&15, row=quad*4+reg)
#pragma unroll
    for (int fr = 0; fr < 8; ++fr) {
        const int row0 = mBase + wr * 128 + fr * 16 + quad * 4;
#pragma unroll
        for (int c = 0; c < 4; ++c) {
            const int col = nBase + wc * 64 + c * 16 + l16;
#pragma unroll
            for (int r = 0; r < 4; ++r) {
                const size_t idx = (size_t)(row0 + r) * N + col;
                if (C_FP32) ((float*)Cv)[idx] = acc[fr][c][r];
                else        ((_Float16*)Cv)[idx] = (_Float16)acc[fr][c][r];
            }
        }
    }
}

// ---------------------------------------------------------------------------
// fp16 GEMM, 128x128 tile (R0-verified m97 structure): used for the Wo
// projection. R14 rationale: at M=4096,N=2560 the 256^2 grid is only 160
// blocks on 256 CUs (96 idle; kernel time = one block's serial 32 K-tiles
// ~69us). This 128^2 kernel gives 640 blocks (2.5/CU, all CUs busy) and
// measured ~15us faster for this shape in R0/R1.
// ---------------------------------------------------------------------------
template <int C_FP32>
__global__ __launch_bounds__(256, 2) void gemm_f16(
    const _Float16* __restrict__ A,
    const _Float16* __restrict__ Bm,
    void* __restrict__ Cv,
    int M, int N, int K)
{
    __shared__ __align__(16) _Float16 As[128 * 32];
    __shared__ __align__(16) _Float16 Bs[128 * 32];

    const int tid  = threadIdx.x;
    const int lane = tid & 63, w = tid >> 6;
    const int wr = w >> 1, wc = w & 1;
    const int quad = lane >> 4, l16 = lane & 15;
    const int mBase = blockIdx.y * 128, nBase = blockIdx.x * 128;

    floatx4 acc[4][4];
    const floatx4 fzero = {0.f, 0.f, 0.f, 0.f};
#pragma unroll
    for (int i = 0; i < 4; ++i)
#pragma unroll
        for (int j = 0; j < 4; ++j) acc[i][j] = fzero;

    const int sRow = lane >> 2;
    const int sCol = (lane & 3) * 8;
    const size_t aRow = (size_t)(mBase + w * 32 + sRow);
    const size_t bRow = (size_t)(nBase + w * 32 + sRow);

    for (int kk = 0; kk < K; kk += 32) {
#pragma unroll
        for (int i = 0; i < 2; ++i) {
            async16(A  + (aRow + i * 16) * K + kk + sCol, &As[(w * 32 + i * 16) * 32]);
            async16(Bm + (bRow + i * 16) * K + kk + sCol, &Bs[(w * 32 + i * 16) * 32]);
        }
        __syncthreads();
        half8 af[4], bfv[4];
#pragma unroll
        for (int i = 0; i < 4; ++i)
            af[i] = *(const half8*)&As[(wr * 64 + i * 16 + l16) * 32 + quad * 8];
#pragma unroll
        for (int j = 0; j < 4; ++j)
            bfv[j] = *(const half8*)&Bs[(wc * 64 + j * 16 + l16) * 32 + quad * 8];
#pragma unroll
        for (int i = 0; i < 4; ++i)
#pragma unroll
            for (int j = 0; j < 4; ++j)
                acc[i][j] = __builtin_amdgcn_mfma_f32_16x16x32_f16(af[i], bfv[j], acc[i][j], 0, 0, 0);
        __syncthreads();
    }

    // epilogue: C/D layout col=lane&15, row=quad*4+reg (m89-verified)
#pragma unroll
    for (int i = 0; i < 4; ++i) {
        const int row0 = mBase + wr * 64 + i * 16 + quad * 4;
#pragma unroll
        for (int j = 0; j < 4; ++j) {
            const int col = nBase + wc * 64 + j * 16 + l16;
#pragma unroll
            for (int r = 0; r < 4; ++r) {
                const size_t idx = (size_t)(row0 + r) * N + col;
                if (C_FP32) ((float*)Cv)[idx] = acc[i][j][r];
                else        ((_Float16*)Cv)[idx] = (_Float16)acc[i][j][r];
            }
        }
    }
}

// ---------------------------------------------------------------------------
// IN-PLACE RMSNorm + RoPE for q/k ONLY (V normalized in transpose_rms_v).
// ---------------------------------------------------------------------------
__global__ __launch_bounds__(256) void rmsrope_inplace(
    _Float16* __restrict__ qkv,        // [4096][4096] fp16
    const float* __restrict__ cosT,    // [S][D] fp32
    const float* __restrict__ sinT,
    const float* __restrict__ qw,      // [D] fp32
    const float* __restrict__ kw)
{
    const int t = blockIdx.x;                // b*S + s
    const int s = t & (S_ - 1);
    const int tid = threadIdx.x, lane = tid & 63, w = tid >> 6;
    _Float16* row = qkv + (size_t)t * QKV_LD;
    const int d0 = lane * 2, d1 = 128 + lane * 2;

    floatx2 c0 = *(const floatx2*)(cosT + (size_t)s * D_ + d0);
    floatx2 c1 = *(const floatx2*)(cosT + (size_t)s * D_ + d1);
    floatx2 s0 = *(const floatx2*)(sinT + (size_t)s * D_ + d0);
    floatx2 s1 = *(const floatx2*)(sinT + (size_t)s * D_ + d1);
    floatx2 qw0 = *(const floatx2*)(qw + d0), qw1 = *(const floatx2*)(qw + d1);
    floatx2 kw0 = *(const floatx2*)(kw + d0), kw1 = *(const floatx2*)(kw + d1);

#pragma unroll
    for (int p = 0; p < 3; ++p) {
        const int v = w + p * 4;             // 0..11, wave-uniform
        _Float16* x = row + v * D_;
        float x0a = (float)x[d0], x0b = (float)x[d0 + 1];
        float x1a = (float)x[d1], x1b = (float)x[d1 + 1];
        float ss = x0a * x0a + x0b * x0b + x1a * x1a + x1b * x1b;
#pragma unroll
        for (int off = 32; off > 0; off >>= 1) ss += __shfl_xor(ss, off, 64);
        const float rinv = rsqrtf(ss * (1.0f / 256.0f) + 1e-6f);
        if (v < 8) {
            const float y0a = x0a * rinv * (1.f + qw0.x), y0b = x0b * rinv * (1.f + qw0.y);
            const float y1a = x1a * rinv * (1.f + qw1.x), y1b = x1b * rinv * (1.f + qw1.y);
            x[d0] = (_Float16)(y0a * c0.x - y1a * s0.x);
            x[d0 + 1] = (_Float16)(y0b * c0.y - y1b * s0.y);
            x[d1] = (_Float16)(y1a * c1.x + y0a * s1.x);
            x[d1 + 1] = (_Float16)(y1b * c1.y + y0b * s1.y);
        } else {
            const float y0a = x0a * rinv * (1.f + kw0.x), y0b = x0b * rinv * (1.f + kw0.y);
            const float y1a = x1a * rinv * (1.f + kw1.x), y1b = x1b * rinv * (1.f + kw1.y);
            x[d0] = (_Float16)(y0a * c0.x - y1a * s0.x);
            x[d0 + 1] = (_Float16)(y0b * c0.y - y1b * s0.y);
            x[d1] = (_Float16)(y1a * c1.x + y0a * s1.x);
            x[d1 + 1] = (_Float16)(y1b * c1.y + y0b * s1.y);
        }
    }
}

// ---------------------------------------------------------------------------
// V transpose WITH fused RMSNorm: reads raw gemm V output from qkv,
// normalizes per token, writes Vt[b][kvh][d][s]. XOR-swizzled LDS transpose.
// ---------------------------------------------------------------------------
__global__ __launch_bounds__(256) void transpose_rms_v(
    const _Float16* __restrict__ qkv, _Float16* __restrict__ Vt)
{
    __shared__ __align__(16) _Float16 Lt[256][64];   // 32 KB, XOR-swizzled cols
    __shared__ float ssq[64][4];
    const int ti = blockIdx.x;              // 0..63 token tile (64 tokens)
    const int kvh = blockIdx.y;             // 0..3
    const int t0 = ti * 64;                 // linear token = b*S + s
    const int b = t0 >> 11;
    const int s0 = t0 & (S_ - 1);
    const int tid = threadIdx.x;
    const int r = tid >> 2, c4 = tid & 3;

    const _Float16* src = qkv + (size_t)(t0 + r) * QKV_LD + 3072 + kvh * D_ + c4 * 64;
    half8 xv[8];
    float ss = 0.f;
#pragma unroll
    for (int i = 0; i < 8; ++i) {
        xv[i] = *(const half8*)(src + i * 8);
#pragma unroll
        for (int j = 0; j < 8; ++j) { const float f = (float)xv[i][j]; ss += f * f; }
    }
    ssq[r][c4] = ss;
    __syncthreads();
    const float tot = ssq[r][0] + ssq[r][1] + ssq[r][2] + ssq[r][3];
    const float rinv = rsqrtf(tot * (1.0f / 256.0f) + 1e-6f);
#pragma unroll
    for (int i = 0; i < 8; ++i)
#pragma unroll
        for (int j = 0; j < 8; ++j) {
            const int d = c4 * 64 + i * 8 + j;
            Lt[d][r ^ ((d & 7) << 3)] = (_Float16)((float)xv[i][j] * rinv);
        }
    __syncthreads();

    const int dd = tid;
    _Float16* dst = Vt + ((size_t)(b * NKV_ + kvh) * D_ + dd) * S_ + s0;
    const int xr = (dd & 7) << 3;
#pragma unroll
    for (int i = 0; i < 8; ++i)
        *(half8*)(dst + ((i * 8) ^ xr)) = *(const half8*)&Lt[dd][i * 8];
}

// ---------------------------------------------------------------------------
// Flash attention v3.5: DPP reductions + interior mask skip + defer-max +
// LPT heavy-first job order + XCD clustering.
// ---------------------------------------------------------------------------
#define PS_STRIDE 40

__global__ __launch_bounds__(256, 2) void attn_kernel(
    const _Float16* __restrict__ qkv,  // [B*S][4096] fp16 (post rms+rope)
    const _Float16* __restrict__ Vt,   // [B][NKV][D][S] fp16
    _Float16* __restrict__ Oa)         // [B*S][NH*D] fp16
{
    __shared__ __align__(16) _Float16 Ks[2][32 * 256];   // 2 x 16 KB
    __shared__ __align__(16) _Float16 Vs[2][256 * 32];   // 2 x 16 KB
    __shared__ __align__(16) _Float16 Ps[4][16 * PS_STRIDE];

    const int idx = blockIdx.x;                   // 0..511
    const int xcd = idx & 7, pos = idx >> 3;      // pos 0..63
    const int b = xcd >> 2;
    const int h0 = (xcd * 2) & 7;
    int qt, h;
    if (pos < 32) { qt = 16 + (pos >> 1); h = h0 + (pos & 1); }
    else          { const int p = pos - 32; qt = 15 - (p >> 1); h = h0 + (p & 1); }
    const int qb = qt * 64;
    const int kvh = h >> 1;                       // repeat_interleave(2)

    const int tid = threadIdx.x, lane = tid & 63, w = tid >> 6;
    const int quad = lane >> 4, l16 = lane & 15;
    const int q0 = qb + w * 16;                   // wave's first query

    const _Float16* Qrow = qkv + ((size_t)(b * S_ + q0 + l16)) * QKV_LD + h * D_;
    half8 qf[8];
#pragma unroll
    for (int kst = 0; kst < 8; ++kst)
        qf[kst] = *(const half8*)(Qrow + kst * 32 + quad * 8);

    floatx4 o[16];
    const floatx4 fzero = {0.f, 0.f, 0.f, 0.f};
#pragma unroll
    for (int dt = 0; dt < 16; ++dt) o[dt] = fzero;
    float mrow[4] = {-50000.f, -50000.f, -50000.f, -50000.f};
    float lrow[4] = {0.f, 0.f, 0.f, 0.f};

    const _Float16* Kbase  = qkv + (size_t)(b * S_) * QKV_LD + 2048 + kvh * D_;
    const _Float16* Vtbase = Vt + (size_t)(b * NKV_ + kvh) * D_ * S_;
    const int kb_start = (qb >= SW_) ? qb - SW_ : 0;
    const int kb_end = qb + 32;  // inclusive

    auto stage = [&](int kb, int bufi) {
#pragma unroll
        for (int p = 0; p < 4; ++p) {
            const int keyl = w * 8 + p * 2 + (lane >> 5);     // 0..31
            const int g = ((lane & 31) - keyl) & 31;          // rotated source chunk
            async16(Kbase + (size_t)(kb + keyl) * QKV_LD + g * 8,
                    &Ks[bufi][(w * 8 + p * 2) * 256]);
        }
#pragma unroll
        for (int p = 0; p < 4; ++p) {
            const int drow = w * 64 + p * 16 + (lane >> 2);   // 0..255
            const int q = lane & 3;
            async16(Vtbase + (size_t)drow * S_ + kb + q * 8,
                    &Vs[bufi][(w * 64 + p * 16) * 32]);
        }
    };

    int buf = 0;
    stage(kb_start, 0);

    for (int kb = kb_start; kb <= kb_end; kb += 32) {
        __syncthreads();
        if (kb + 32 <= kb_end) stage(kb + 32, buf ^ 1);

        if ((kb <= q0 + 15) && (kb + 31 >= q0 - (SW_ - 1))) {
            floatx4 sacc[2];
            sacc[0] = fzero; sacc[1] = fzero;
            __builtin_amdgcn_s_setprio(1);
#pragma unroll
            for (int jt = 0; jt < 2; ++jt) {
                const int keyl = jt * 16 + l16;
#pragma unroll
                for (int kst = 0; kst < 8; ++kst) {
                    const int crot = (kst * 4 + quad + keyl) & 31;
                    half8 kf = *(const half8*)&Ks[buf][keyl * 256 + crot * 8];
                    sacc[jt] = __builtin_amdgcn_mfma_f32_16x16x32_f16(qf[kst], kf, sacc[jt], 0, 0, 0);
                }
            }
            __builtin_amdgcn_s_setprio(0);

            const int qq0 = q0 + quad * 4;
            const bool interior = (kb >= q0 - (SW_ - 16)) && (kb + 31 <= q0);
            float sval[2][4], tmax[4];
            if (interior) {
#pragma unroll
                for (int r = 0; r < 4; ++r)
                    tmax[r] = fmaxf(sacc[0][r], sacc[1][r]);
#pragma unroll
                for (int jt = 0; jt < 2; ++jt)
#pragma unroll
                    for (int r = 0; r < 4; ++r) sval[jt][r] = sacc[jt][r];
            } else {
#pragma unroll
                for (int r = 0; r < 4; ++r) tmax[r] = -1e30f;
#pragma unroll
                for (int jt = 0; jt < 2; ++jt) {
                    const int kg = kb + jt * 16 + l16;
#pragma unroll
                    for (int r = 0; r < 4; ++r) {
                        const int qg = qq0 + r;
                        const bool ok = (unsigned)(qg - kg) < (unsigned)SW_;
                        const float vv = ok ? sacc[jt][r] : -1e30f;
                        sval[jt][r] = vv;
                        tmax[r] = fmaxf(tmax[r], vv);
                    }
                }
            }
            float alpha[4];
            bool need = false;
#pragma unroll
            for (int r = 0; r < 4; ++r) {
                const float t = red16_max(tmax[r]);
                const float mold = mrow[r];
                const float mnew = (t > mold + 8.f) ? t : mold;
                alpha[r] = __expf(mold - mnew);
                need |= (mnew != mold);
                mrow[r] = mnew;
                lrow[r] *= alpha[r];
            }
            if (__any(need)) {
#pragma unroll
                for (int dt = 0; dt < 16; ++dt)
#pragma unroll
                    for (int r = 0; r < 4; ++r) o[dt][r] *= alpha[r];
            }
            float rsum[4] = {0.f, 0.f, 0.f, 0.f};
#pragma unroll
            for (int jt = 0; jt < 2; ++jt)
#pragma unroll
                for (int r = 0; r < 4; ++r) {
                    const float pv = __expf(sval[jt][r] - mrow[r]);
                    rsum[r] += pv;
                    Ps[w][(quad * 4 + r) * PS_STRIDE + jt * 16 + l16] = (_Float16)pv;
                }
#pragma unroll
            for (int r = 0; r < 4; ++r)
                lrow[r] += red16_sum(rsum[r]);

            half8 pa = *(const half8*)&Ps[w][l16 * PS_STRIDE + quad * 8];
            __builtin_amdgcn_s_setprio(1);
#pragma unroll
            for (int dt = 0; dt < 16; ++dt) {
                half8 vf = *(const half8*)&Vs[buf][(dt * 16 + l16) * 32 + quad * 8];
                o[dt] = __builtin_amdgcn_mfma_f32_16x16x32_f16(pa, vf, o[dt], 0, 0, 0);
            }
            __builtin_amdgcn_s_setprio(0);
        }
        buf ^= 1;
    }

    const int qrow = q0 + quad * 4;
#pragma unroll
    for (int r = 0; r < 4; ++r) {
        const float inv = (lrow[r] > 0.f) ? (1.0f / lrow[r]) : 0.f;
        _Float16* orow = Oa + ((size_t)(b * S_ + qrow + r)) * (NH_ * D_) + h * D_;
#pragma unroll
        for (int dt = 0; dt < 16; ++dt)
            orow[dt * 16 + l16] = (_Float16)(o[dt][r] * inv);
    }
}

// ---------------------------------------------------------------------------
extern "C" void kernel_launch(void* const* d_in, const int* in_sizes, int n_in,
                              void* d_out, int out_size, void* d_ws, size_t ws_size,
                              hipStream_t stream)
{
    (void)in_sizes; (void)n_in; (void)out_size; (void)ws_size;
    const float* hid  = (const float*)d_in[0];
    // d_in[1] = attention_mask (unused: analytic causal+window mask is exact)
    const float* cosT = (const float*)d_in[2];
    const float* sinT = (const float*)d_in[3];
    const float* Wq   = (const float*)d_in[4];
    const float* Wk   = (const float*)d_in[5];
    const float* Wv   = (const float*)d_in[6];
    const float* Wo   = (const float*)d_in[7];
    const float* qw   = (const float*)d_in[8];
    const float* kw   = (const float*)d_in[9];
    float* out = (float*)d_out;

    // workspace layout (bytes; ~111 MB total)
    char* ws = (char*)d_ws;
    _Float16* qkv  = (_Float16*)(ws);                      // 33,554,432  [4096][4096]
    _Float16* attn = (_Float16*)(ws + 33554432ull);        // 16,777,216  [4096][2048]
    _Float16* hidH = (_Float16*)(ws + 50331648ull);        // 20,971,520  [4096][2560]
    _Float16* wQKV = (_Float16*)(ws + 71303168ull);        // 20,971,520  [4096][2560]
    _Float16* woH  = (_Float16*)(ws + 92274688ull);        // 10,485,760  [2560][2048]
    _Float16* Vt   = (_Float16*)(ws + 102760448ull);       //  8,388,608  [B][NKV][D][S]

    // 0) all fp32 -> fp16 conversions in one launch
    conv_all<<<dim3(512, 5), 256, 0, stream>>>(
        hid, Wq, Wk, Wv, Wo,
        hidH, wQKV, wQKV + (size_t)2048 * 2560, wQKV + (size_t)3072 * 2560, woH);

    // 1) QKV projection (fp16 MFMA, 256^2 8-phase): -> fp16 [4096][4096]
    gemm256<0><<<dim3(256), 512, 0, stream>>>(hidH, wQKV, qkv, 4096, 4096, 2560, 16);
    // 2) V transpose + fused V-RMSNorm -> Vt (reads raw gemm output)
    transpose_rms_v<<<dim3(64, 4), 256, 0, stream>>>(qkv, Vt);
    // 3) in-place RMSNorm + RoPE on q/k heads only
    rmsrope_inplace<<<4096, 256, 0, stream>>>(qkv, cosT, sinT, qw, kw);
    // 4) flash attention v3.5 (DPP reductions + interior mask skip + LPT)
    attn_kernel<<<dim3(512), 256, 0, stream>>>(qkv, Vt, attn);
    // 5) output projection: fp16 [4096,2048] @ Wo^T -> fp32 out, 128^2 tiles
    //    (640 blocks fill all 256 CUs; the 256^2 grid was only 160 blocks)
    gemm_f16<1><<<dim3(20, 32), 256, 0, stream>>>(attn, woH, out, 4096, 2560, 2048);
}